// Round 7
// baseline (312.171 us; speedup 1.0000x reference)
//
#include <hip/hip_runtime.h>
#include <hip/hip_bf16.h>

#define LOG2E 1.4426950408889634f

typedef __bf16 bf16x8 __attribute__((ext_vector_type(8)));
typedef __bf16 bf16x4 __attribute__((ext_vector_type(4)));
typedef __bf16 bf16x2 __attribute__((ext_vector_type(2)));
typedef float  floatx4 __attribute__((ext_vector_type(4)));

__device__ __forceinline__ floatx4 mfma16(bf16x8 a, bf16x8 b, floatx4 c) {
  return __builtin_amdgcn_mfma_f32_16x16x32_bf16(a, b, c, 0, 0, 0);
}

// async global->LDS, 16B per lane. Dest = wave-uniform base + lane*16.
__device__ __forceinline__ void load_lds16(const __bf16* g, __bf16* l) {
  __builtin_amdgcn_global_load_lds(
      (const __attribute__((address_space(1))) void*)g,
      (__attribute__((address_space(3))) void*)l, 16, 0, 0);
}

__device__ __forceinline__ unsigned pack_bf16(float a, float b) {
  bf16x2 t = {(__bf16)a, (__bf16)b};
  return *(unsigned*)&t;
}

// ---------------------------------------------------------------------------
// Fold LoRA into weights, emit W_eff^T bf16 [ncols][1024].
// ---------------------------------------------------------------------------
__global__ __launch_bounds__(256)
void fold_wt(const float* __restrict__ W, const float* __restrict__ La,
             const float* __restrict__ Lb, __bf16* __restrict__ WT, int ncols) {
  __shared__ float tile[64][65];
  __shared__ float sLb[8][64];
  const int kt = blockIdx.y * 64, nt = blockIdx.x * 64;
  const int tid = threadIdx.x;
  const int tx = tid & 63, ty = tid >> 6;

  float rLa[8];
  *(float4*)&rLa[0] = *(const float4*)(La + (size_t)(kt + tx) * 8);
  *(float4*)&rLa[4] = *(const float4*)(La + (size_t)(kt + tx) * 8 + 4);

#pragma unroll
  for (int rep = 0; rep < 2; rep++) {
    int idx = tid + rep * 256;
    sLb[idx >> 6][idx & 63] = Lb[(size_t)(idx >> 6) * ncols + nt + (idx & 63)];
  }
#pragma unroll
  for (int rep = 0; rep < 16; rep++) {
    int i = rep * 4 + ty;
    tile[i][tx] = W[(size_t)(kt + i) * ncols + nt + tx];
  }
  __syncthreads();
#pragma unroll
  for (int rep = 0; rep < 16; rep++) {
    int i = rep * 4 + ty;
    int n = nt + i, k = kt + tx;
    float acc = tile[tx][i];
#pragma unroll
    for (int r = 0; r < 8; r++)
      acc += 2.0f * rLa[r] * sLb[r][i];  // LORA_SCALING = 2
    WT[(size_t)n * 1024 + k] = (__bf16)acc;
  }
}

__global__ __launch_bounds__(256)
void cast_x(const float* __restrict__ x, __bf16* __restrict__ o) {
  int i = blockIdx.x * 256 + threadIdx.x;
  float4 v = ((const float4*)x)[i];
  bf16x4 r = {(__bf16)v.x, (__bf16)v.y, (__bf16)v.z, (__bf16)v.w};
  ((bf16x4*)o)[i] = r;
}

// ---------------------------------------------------------------------------
// Fused QKV projection, swapped orientation: D[p][s] = sum_k WT[p][k] X[s][k].
// 128x128 tiles, BK=64, global_load_lds staging, XOR-swizzled LDS.
// ---------------------------------------------------------------------------
__global__ __launch_bounds__(256)
void gemm_qkv(const __bf16* __restrict__ WT, const __bf16* __restrict__ X,
              const float* __restrict__ bias, __bf16* __restrict__ qk,
              __bf16* __restrict__ vtb) {
  const int K = 1024;
  __shared__ alignas(16) __bf16 As[128 * 64];
  __shared__ alignas(16) __bf16 Bs[128 * 64];
  const int tid = threadIdx.x;
  const int wave = tid >> 6, lane = tid & 63;
  const int wm = wave >> 1, wn = wave & 1;
  const int quad = lane >> 4, l15 = lane & 15;
  const int p0 = blockIdx.y * 128, s0 = blockIdx.x * 128;
  const int srow8 = lane >> 3, sc8 = lane & 7;
  const int sswz = sc8 ^ srow8;

  floatx4 acc[4][4] = {};

  for (int kb = 0; kb < K; kb += 64) {
    __syncthreads();
#pragma unroll
    for (int t = 0; t < 4; t++) {
      int rbase = (wave * 4 + t) * 8;
      int row = rbase + srow8;
      load_lds16(WT + (size_t)(p0 + row) * K + kb + sswz * 8, As + rbase * 64);
      load_lds16(X + (size_t)(s0 + row) * K + kb + sswz * 8, Bs + rbase * 64);
    }
    __syncthreads();
#pragma unroll
    for (int ks = 0; ks < 2; ks++) {
      bf16x8 af[4], bfv[4];
#pragma unroll
      for (int t = 0; t < 4; t++) {
        int ra = wm * 64 + t * 16 + l15;
        int rb = wn * 64 + t * 16 + l15;
        int ch = (ks * 4 + quad) ^ (l15 & 7);
        af[t]  = *(const bf16x8*)(As + ra * 64 + ch * 8);
        bfv[t] = *(const bf16x8*)(Bs + rb * 64 + ch * 8);
      }
#pragma unroll
      for (int mi = 0; mi < 4; mi++)
#pragma unroll
        for (int ni = 0; ni < 4; ni++)
          acc[mi][ni] = mfma16(af[mi], bfv[ni], acc[mi][ni]);
    }
  }

#pragma unroll
  for (int mi = 0; mi < 4; mi++) {
#pragma unroll
    for (int ni = 0; ni < 4; ni++) {
      int pb = p0 + wm * 64 + mi * 16 + quad * 4;  // channel base (mult of 4)
      int s  = s0 + wn * 64 + ni * 16 + l15;       // token
      int b = s >> 11, s2 = s & 2047;
      if (p0 < 2048) {  // q/k: uniform per block
        int part = pb >> 10, h = (pb & 1023) >> 6, dhb = pb & 63;
        bf16x4 o = {(__bf16)(acc[mi][ni][0] + bias[pb]),
                    (__bf16)(acc[mi][ni][1] + bias[pb + 1]),
                    (__bf16)(acc[mi][ni][2] + bias[pb + 2]),
                    (__bf16)(acc[mi][ni][3] + bias[pb + 3])};
        *(bf16x4*)(qk + (size_t)part * 4194304 +
                   ((size_t)((b * 16 + h) * 2048 + s2)) * 64 + dhb) = o;
      } else {  // v -> v^T
        int h = (pb & 1023) >> 6, dhb = pb & 63;
#pragma unroll
        for (int r = 0; r < 4; r++)
          vtb[((size_t)((b * 16 + h) * 64 + dhb + r)) * 2048 + s2] =
              (__bf16)(acc[mi][ni][r] + bias[pb + r]);
      }
    }
  }
}

// ---------------------------------------------------------------------------
// Output projection, 64x128 tile: grid (8, 64) = 512 blocks.  fp32 out + bias.
// ---------------------------------------------------------------------------
__global__ __launch_bounds__(256)
void gemm_proj(const __bf16* __restrict__ A, const __bf16* __restrict__ BT,
               const float* __restrict__ bias, float* __restrict__ Cout, int N) {
  const int K = 1024;
  __shared__ alignas(16) __bf16 As[64 * 64];
  __shared__ alignas(16) __bf16 Bs[128 * 64];
  const int tid = threadIdx.x;
  const int wave = tid >> 6, lane = tid & 63;
  const int wm = wave >> 1, wn = wave & 1;
  const int quad = lane >> 4, l15 = lane & 15;
  const int m0 = blockIdx.y * 64, n0 = blockIdx.x * 128;
  const int srow8 = lane >> 3, sc8 = lane & 7;
  const int sswz = sc8 ^ srow8;

  floatx4 acc[2][4] = {};

  for (int kb = 0; kb < K; kb += 64) {
    __syncthreads();
#pragma unroll
    for (int t = 0; t < 2; t++) {
      int rbase = (wave * 2 + t) * 8;
      load_lds16(A + (size_t)(m0 + rbase + srow8) * K + kb + sswz * 8,
                 As + rbase * 64);
    }
#pragma unroll
    for (int t = 0; t < 4; t++) {
      int rbase = (wave * 4 + t) * 8;
      load_lds16(BT + (size_t)(n0 + rbase + srow8) * K + kb + sswz * 8,
                 Bs + rbase * 64);
    }
    __syncthreads();
#pragma unroll
    for (int ks = 0; ks < 2; ks++) {
      bf16x8 af[2], bfv[4];
      int ch = (ks * 4 + quad) ^ (l15 & 7);
#pragma unroll
      for (int t = 0; t < 2; t++)
        af[t] = *(const bf16x8*)(As + (wm * 32 + t * 16 + l15) * 64 + ch * 8);
#pragma unroll
      for (int t = 0; t < 4; t++)
        bfv[t] = *(const bf16x8*)(Bs + (wn * 64 + t * 16 + l15) * 64 + ch * 8);
#pragma unroll
      for (int mi = 0; mi < 2; mi++)
#pragma unroll
        for (int ni = 0; ni < 4; ni++)
          acc[mi][ni] = mfma16(af[mi], bfv[ni], acc[mi][ni]);
    }
  }

#pragma unroll
  for (int mi = 0; mi < 2; mi++)
#pragma unroll
    for (int ni = 0; ni < 4; ni++) {
      int n = n0 + wn * 64 + ni * 16 + l15;
#pragma unroll
      for (int r = 0; r < 4; r++) {
        int m = m0 + wm * 32 + mi * 16 + quad * 4 + r;
        Cout[(size_t)m * N + n] = acc[mi][ni][r] + bias[n];
      }
    }
}

// ---------------------------------------------------------------------------
// Barrier-free, LDS-free causal flash attention v6.
// 256-thread blocks = 4 INDEPENDENT waves (no __syncthreads), each wave one
// 32-q strip (R5 structure, 92 us @ ~4 resident waves/CU).  Packing 4 waves
// per workgroup tests the workgroup-slot-cap theory: same 2048 waves, 512
// blocks.  bid=(63-j)*8+bhg: all waves in a block share strip length j (LPT),
// bh = bhg*4+wave, XCD bid%8=bhg -> 4 heads/XCD (2 MB K/V, L2-resident).
// Masks BEFORE scale like the reference: masked -> -1e9/8 = -1.25e8.
// ---------------------------------------------------------------------------
__global__ __launch_bounds__(256, 3)
void flash_attn(const __bf16* __restrict__ q, const __bf16* __restrict__ k,
                const __bf16* __restrict__ vt, const int* __restrict__ amask,
                __bf16* __restrict__ ctx) {
  const int S = 2048;
  const int bid = blockIdx.x;
  const int wave = threadIdx.x >> 6, lane = threadIdx.x & 63;
  const int j = 63 - (bid >> 3);    // strip index, heaviest first
  const int bh = (bid & 7) * 4 + wave;
  const int b = bh >> 4, h = bh & 15;
  const int quad = lane >> 4, l15 = lane & 15;
  const int q0 = j * 32;

  const __bf16* qp  = q  + (size_t)bh * S * 64;
  const __bf16* kp0 = k  + (size_t)bh * S * 64;
  const __bf16* vp0 = vt + (size_t)bh * 64 * S;

  bf16x8 qf[2][2];  // [mt][ks]
#pragma unroll
  for (int mt = 0; mt < 2; mt++)
#pragma unroll
    for (int ks = 0; ks < 2; ks++)
      qf[mt][ks] = *(const bf16x8*)(qp + (size_t)(q0 + mt * 16 + l15) * 64 +
                                    ks * 32 + quad * 8);

  float mrun[2] = {-3.0e38f, -3.0e38f}, lrun[2] = {0.0f, 0.0f};
  floatx4 oacc[2][4] = {};
  const int nch = ((q0 + 31) >> 6) + 1;  // 64-key chunks

  // shuffle sources for P transform (same l15 column, two quads)
  const int bsel = (quad & 1) * 2;
  const int srcA = bsel * 16 + l15;
  const int srcB = (bsel + 1) * 16 + l15;
  const bool hiTile = (quad >> 1) != 0;

  for (int c = 0; c < nch; c++) {
    const __bf16* kp = kp0 + (size_t)c * 64 * 64;
    floatx4 st[4][2] = {};  // st[key-tile][q-tile]; col(l15)=q, row(quad*4+r)=key
#pragma unroll
    for (int ks = 0; ks < 2; ks++) {
      bf16x8 kf[4];
#pragma unroll
      for (int nt = 0; nt < 4; nt++)
        kf[nt] = *(const bf16x8*)(kp + (size_t)(nt * 16 + l15) * 64 +
                                  ks * 32 + quad * 8);
#pragma unroll
      for (int nt = 0; nt < 4; nt++) {
        st[nt][0] = mfma16(kf[nt], qf[0][ks], st[nt][0]);
        st[nt][1] = mfma16(kf[nt], qf[1][ks], st[nt][1]);
      }
    }
    unsigned long long pm = __ballot(amask[b * S + c * 64 + lane] == 0);

    if (c == nch - 1) {  // wave-uniform: only last chunk can cross diagonal
#pragma unroll
      for (int nt = 0; nt < 4; nt++) {
        int kl = nt * 16 + quad * 4;
        int keyg = c * 64 + kl;
#pragma unroll
        for (int r = 0; r < 4; r++) {
          bool pad = (pm >> (kl + r)) & 1ull;
#pragma unroll
          for (int mt = 0; mt < 2; mt++) {
            float sv = st[nt][mt][r] * 0.125f;
            bool masked = pad || (keyg + r > q0 + mt * 16 + l15);
            st[nt][mt][r] = masked ? -1.25e8f : sv;
          }
        }
      }
    } else {
#pragma unroll
      for (int nt = 0; nt < 4; nt++) {
        int kl = nt * 16 + quad * 4;
#pragma unroll
        for (int r = 0; r < 4; r++) {
          bool pad = (pm >> (kl + r)) & 1ull;
#pragma unroll
          for (int mt = 0; mt < 2; mt++) {
            float sv = st[nt][mt][r] * 0.125f;
            st[nt][mt][r] = pad ? -1.25e8f : sv;
          }
        }
      }
    }

    // online softmax (per q = l15), tree reductions
    float al[2];
#pragma unroll
    for (int mt = 0; mt < 2; mt++) {
      float m4[4];
#pragma unroll
      for (int nt = 0; nt < 4; nt++)
        m4[nt] = fmaxf(fmaxf(st[nt][mt][0], st[nt][mt][1]),
                       fmaxf(st[nt][mt][2], st[nt][mt][3]));
      float rm = fmaxf(fmaxf(m4[0], m4[1]), fmaxf(m4[2], m4[3]));
      rm = fmaxf(rm, __shfl_xor(rm, 16, 64));
      rm = fmaxf(rm, __shfl_xor(rm, 32, 64));
      float mnew = fmaxf(mrun[mt], rm);
      al[mt] = exp2f((mrun[mt] - mnew) * LOG2E);
      mrun[mt] = mnew;
      float s4[4];
#pragma unroll
      for (int nt = 0; nt < 4; nt++) {
        float p0 = exp2f((st[nt][mt][0] - mnew) * LOG2E);
        float p1 = exp2f((st[nt][mt][1] - mnew) * LOG2E);
        float p2 = exp2f((st[nt][mt][2] - mnew) * LOG2E);
        float p3 = exp2f((st[nt][mt][3] - mnew) * LOG2E);
        st[nt][mt][0] = p0; st[nt][mt][1] = p1;
        st[nt][mt][2] = p2; st[nt][mt][3] = p3;
        s4[nt] = (p0 + p1) + (p2 + p3);
      }
      float rs = (s4[0] + s4[1]) + (s4[2] + s4[3]);
      rs += __shfl_xor(rs, 16, 64);
      rs += __shfl_xor(rs, 32, 64);
      lrun[mt] = lrun[mt] * al[mt] + rs;
    }

    // rescale O (alpha per O-row quad*4+r, fetched cross-lane)
#pragma unroll
    for (int mt = 0; mt < 2; mt++) {
      float ar[4];
#pragma unroll
      for (int r = 0; r < 4; r++) ar[r] = __shfl(al[mt], quad * 4 + r, 64);
#pragma unroll
      for (int nd = 0; nd < 4; nd++)
#pragma unroll
        for (int r = 0; r < 4; r++) oacc[mt][nd][r] *= ar[r];
    }

    // pack P to bf16 pairs: pk[nt][mt] = {keys r0r1, r2r3} for q=l15
    unsigned pkLo[4][2], pkHi[4][2];
#pragma unroll
    for (int nt = 0; nt < 4; nt++)
#pragma unroll
      for (int mt = 0; mt < 2; mt++) {
        pkLo[nt][mt] = pack_bf16(st[nt][mt][0], st[nt][mt][1]);
        pkHi[nt][mt] = pack_bf16(st[nt][mt][2], st[nt][mt][3]);
      }

    // O += P V over two 32-key subchunks; P A-frag via shuffles
#pragma unroll
    for (int s = 0; s < 2; s++) {
      bf16x8 pf[2];
#pragma unroll
      for (int mt = 0; mt < 2; mt++) {
        int t0 = s * 2, t1 = s * 2 + 1;
        unsigned u0a = __shfl((int)pkLo[t0][mt], srcA, 64);
        unsigned u0b = __shfl((int)pkLo[t1][mt], srcA, 64);
        unsigned u1a = __shfl((int)pkHi[t0][mt], srcA, 64);
        unsigned u1b = __shfl((int)pkHi[t1][mt], srcA, 64);
        unsigned u2a = __shfl((int)pkLo[t0][mt], srcB, 64);
        unsigned u2b = __shfl((int)pkLo[t1][mt], srcB, 64);
        unsigned u3a = __shfl((int)pkHi[t0][mt], srcB, 64);
        unsigned u3b = __shfl((int)pkHi[t1][mt], srcB, 64);
        unsigned u[4] = {hiTile ? u0b : u0a, hiTile ? u1b : u1a,
                         hiTile ? u2b : u2a, hiTile ? u3b : u3a};
        pf[mt] = *(bf16x8*)u;
      }
      const __bf16* vp = vp0 + c * 64 + s * 32;
#pragma unroll
      for (int nd = 0; nd < 4; nd++) {
        bf16x8 vf = *(const bf16x8*)(vp + (size_t)(nd * 16 + l15) * S + quad * 8);
        oacc[0][nd] = mfma16(pf[0], vf, oacc[0][nd]);
        oacc[1][nd] = mfma16(pf[1], vf, oacc[1][nd]);
      }
    }
  }

  // epilogue: ctx[b][s][h*64+dh] = O / l ;  O rows = quad*4+r
#pragma unroll
  for (int mt = 0; mt < 2; mt++) {
    float lr[4];
#pragma unroll
    for (int r = 0; r < 4; r++)
      lr[r] = 1.0f / __shfl(lrun[mt], quad * 4 + r, 64);
#pragma unroll
    for (int nd = 0; nd < 4; nd++) {
#pragma unroll
      for (int r = 0; r < 4; r++) {
        int s = q0 + mt * 16 + quad * 4 + r;
        int dh = nd * 16 + l15;
        ctx[((size_t)(b * 2048 + s)) * 1024 + h * 64 + dh] =
            (__bf16)(oacc[mt][nd][r] * lr[r]);
      }
    }
  }
}

// ---------------------------------------------------------------------------
extern "C" void kernel_launch(void* const* d_in, const int* in_sizes, int n_in,
                              void* d_out, int out_size, void* d_ws, size_t ws_size,
                              hipStream_t stream) {
  const float* x  = (const float*)d_in[0];
  const int*   am = (const int*)d_in[1];
  const float* Wq = (const float*)d_in[2];
  const float* bq = (const float*)d_in[3];
  const float* Aq = (const float*)d_in[4];
  const float* Bq = (const float*)d_in[5];
  const float* Wp = (const float*)d_in[6];
  const float* bp = (const float*)d_in[7];
  const float* Ap = (const float*)d_in[8];
  const float* Bp = (const float*)d_in[9];

  __bf16* wqkvT = (__bf16*)d_ws;                       // [3072][1024]
  __bf16* wpT   = wqkvT + (size_t)3072 * 1024;         // [1024][1024]
  __bf16* xbf   = wpT   + (size_t)1024 * 1024;         // [4096][1024]
  __bf16* qbuf  = xbf   + (size_t)4096 * 1024;         // [2][16][2048][64] (+kbuf)
  __bf16* vtbuf = qbuf  + (size_t)2 * 4194304;         // [2][16][64][2048]
  __bf16* ctxb  = vtbuf + (size_t)4194304;             // [4096][1024]

  fold_wt<<<dim3(48, 16), 256, 0, stream>>>(Wq, Aq, Bq, wqkvT, 3072);
  fold_wt<<<dim3(16, 16), 256, 0, stream>>>(Wp, Ap, Bp, wpT, 1024);
  cast_x<<<4096, 256, 0, stream>>>(x, xbf);

  gemm_qkv<<<dim3(32, 24), 256, 0, stream>>>(wqkvT, xbf, bq, qbuf, vtbuf);
  flash_attn<<<512, 256, 0, stream>>>(qbuf, qbuf + 4194304, vtbuf, am, ctxb);
  gemm_proj<<<dim3(8, 64), 256, 0, stream>>>(ctxb, wpT, bp, (float*)d_out, 1024);
}

// Round 8
// 253.825 us; speedup vs baseline: 1.2299x; 1.2299x over previous
//
#include <hip/hip_runtime.h>
#include <hip/hip_bf16.h>

#define LOG2E 1.4426950408889634f

typedef __bf16 bf16x8 __attribute__((ext_vector_type(8)));
typedef __bf16 bf16x4 __attribute__((ext_vector_type(4)));
typedef __bf16 bf16x2 __attribute__((ext_vector_type(2)));
typedef float  floatx4 __attribute__((ext_vector_type(4)));

__device__ __forceinline__ floatx4 mfma16(bf16x8 a, bf16x8 b, floatx4 c) {
  return __builtin_amdgcn_mfma_f32_16x16x32_bf16(a, b, c, 0, 0, 0);
}

// async global->LDS, 16B per lane. Dest = wave-uniform base + lane*16.
__device__ __forceinline__ void load_lds16(const __bf16* g, __bf16* l) {
  __builtin_amdgcn_global_load_lds(
      (const __attribute__((address_space(1))) void*)g,
      (__attribute__((address_space(3))) void*)l, 16, 0, 0);
}

__device__ __forceinline__ unsigned pack_bf16(float a, float b) {
  bf16x2 t = {(__bf16)a, (__bf16)b};
  return *(unsigned*)&t;
}

// ---------------------------------------------------------------------------
// Fold LoRA into weights, emit W_eff^T bf16 [ncols][1024].
// ---------------------------------------------------------------------------
__global__ __launch_bounds__(256)
void fold_wt(const float* __restrict__ W, const float* __restrict__ La,
             const float* __restrict__ Lb, __bf16* __restrict__ WT, int ncols) {
  __shared__ float tile[64][65];
  __shared__ float sLb[8][64];
  const int kt = blockIdx.y * 64, nt = blockIdx.x * 64;
  const int tid = threadIdx.x;
  const int tx = tid & 63, ty = tid >> 6;

  float rLa[8];
  *(float4*)&rLa[0] = *(const float4*)(La + (size_t)(kt + tx) * 8);
  *(float4*)&rLa[4] = *(const float4*)(La + (size_t)(kt + tx) * 8 + 4);

#pragma unroll
  for (int rep = 0; rep < 2; rep++) {
    int idx = tid + rep * 256;
    sLb[idx >> 6][idx & 63] = Lb[(size_t)(idx >> 6) * ncols + nt + (idx & 63)];
  }
#pragma unroll
  for (int rep = 0; rep < 16; rep++) {
    int i = rep * 4 + ty;
    tile[i][tx] = W[(size_t)(kt + i) * ncols + nt + tx];
  }
  __syncthreads();
#pragma unroll
  for (int rep = 0; rep < 16; rep++) {
    int i = rep * 4 + ty;
    int n = nt + i, k = kt + tx;
    float acc = tile[tx][i];
#pragma unroll
    for (int r = 0; r < 8; r++)
      acc += 2.0f * rLa[r] * sLb[r][i];  // LORA_SCALING = 2
    WT[(size_t)n * 1024 + k] = (__bf16)acc;
  }
}

__global__ __launch_bounds__(256)
void cast_x(const float* __restrict__ x, __bf16* __restrict__ o) {
  int i = blockIdx.x * 256 + threadIdx.x;
  float4 v = ((const float4*)x)[i];
  bf16x4 r = {(__bf16)v.x, (__bf16)v.y, (__bf16)v.z, (__bf16)v.w};
  ((bf16x4*)o)[i] = r;
}

// ---------------------------------------------------------------------------
// Fused QKV projection, swapped orientation: D[p][s] = sum_k WT[p][k] X[s][k].
// 128x128 tiles, BK=64, global_load_lds staging, XOR-swizzled LDS.
// ---------------------------------------------------------------------------
__global__ __launch_bounds__(256)
void gemm_qkv(const __bf16* __restrict__ WT, const __bf16* __restrict__ X,
              const float* __restrict__ bias, __bf16* __restrict__ qk,
              __bf16* __restrict__ vtb) {
  const int K = 1024;
  __shared__ alignas(16) __bf16 As[128 * 64];
  __shared__ alignas(16) __bf16 Bs[128 * 64];
  const int tid = threadIdx.x;
  const int wave = tid >> 6, lane = tid & 63;
  const int wm = wave >> 1, wn = wave & 1;
  const int quad = lane >> 4, l15 = lane & 15;
  const int p0 = blockIdx.y * 128, s0 = blockIdx.x * 128;
  const int srow8 = lane >> 3, sc8 = lane & 7;
  const int sswz = sc8 ^ srow8;

  floatx4 acc[4][4] = {};

  for (int kb = 0; kb < K; kb += 64) {
    __syncthreads();
#pragma unroll
    for (int t = 0; t < 4; t++) {
      int rbase = (wave * 4 + t) * 8;
      int row = rbase + srow8;
      load_lds16(WT + (size_t)(p0 + row) * K + kb + sswz * 8, As + rbase * 64);
      load_lds16(X + (size_t)(s0 + row) * K + kb + sswz * 8, Bs + rbase * 64);
    }
    __syncthreads();
#pragma unroll
    for (int ks = 0; ks < 2; ks++) {
      bf16x8 af[4], bfv[4];
#pragma unroll
      for (int t = 0; t < 4; t++) {
        int ra = wm * 64 + t * 16 + l15;
        int rb = wn * 64 + t * 16 + l15;
        int ch = (ks * 4 + quad) ^ (l15 & 7);
        af[t]  = *(const bf16x8*)(As + ra * 64 + ch * 8);
        bfv[t] = *(const bf16x8*)(Bs + rb * 64 + ch * 8);
      }
#pragma unroll
      for (int mi = 0; mi < 4; mi++)
#pragma unroll
        for (int ni = 0; ni < 4; ni++)
          acc[mi][ni] = mfma16(af[mi], bfv[ni], acc[mi][ni]);
    }
  }

#pragma unroll
  for (int mi = 0; mi < 4; mi++) {
#pragma unroll
    for (int ni = 0; ni < 4; ni++) {
      int pb = p0 + wm * 64 + mi * 16 + quad * 4;  // channel base (mult of 4)
      int s  = s0 + wn * 64 + ni * 16 + l15;       // token
      int b = s >> 11, s2 = s & 2047;
      if (p0 < 2048) {  // q/k: uniform per block
        int part = pb >> 10, h = (pb & 1023) >> 6, dhb = pb & 63;
        bf16x4 o = {(__bf16)(acc[mi][ni][0] + bias[pb]),
                    (__bf16)(acc[mi][ni][1] + bias[pb + 1]),
                    (__bf16)(acc[mi][ni][2] + bias[pb + 2]),
                    (__bf16)(acc[mi][ni][3] + bias[pb + 3])};
        *(bf16x4*)(qk + (size_t)part * 4194304 +
                   ((size_t)((b * 16 + h) * 2048 + s2)) * 64 + dhb) = o;
      } else {  // v -> v^T
        int h = (pb & 1023) >> 6, dhb = pb & 63;
#pragma unroll
        for (int r = 0; r < 4; r++)
          vtb[((size_t)((b * 16 + h) * 64 + dhb + r)) * 2048 + s2] =
              (__bf16)(acc[mi][ni][r] + bias[pb + r]);
      }
    }
  }
}

// ---------------------------------------------------------------------------
// Output projection, 64x128 tile: grid (8, 64) = 512 blocks.  fp32 out + bias.
// ---------------------------------------------------------------------------
__global__ __launch_bounds__(256)
void gemm_proj(const __bf16* __restrict__ A, const __bf16* __restrict__ BT,
               const float* __restrict__ bias, float* __restrict__ Cout, int N) {
  const int K = 1024;
  __shared__ alignas(16) __bf16 As[64 * 64];
  __shared__ alignas(16) __bf16 Bs[128 * 64];
  const int tid = threadIdx.x;
  const int wave = tid >> 6, lane = tid & 63;
  const int wm = wave >> 1, wn = wave & 1;
  const int quad = lane >> 4, l15 = lane & 15;
  const int m0 = blockIdx.y * 64, n0 = blockIdx.x * 128;
  const int srow8 = lane >> 3, sc8 = lane & 7;
  const int sswz = sc8 ^ srow8;

  floatx4 acc[2][4] = {};

  for (int kb = 0; kb < K; kb += 64) {
    __syncthreads();
#pragma unroll
    for (int t = 0; t < 2; t++) {
      int rbase = (wave * 2 + t) * 8;
      load_lds16(A + (size_t)(m0 + rbase + srow8) * K + kb + sswz * 8,
                 As + rbase * 64);
    }
#pragma unroll
    for (int t = 0; t < 4; t++) {
      int rbase = (wave * 4 + t) * 8;
      load_lds16(BT + (size_t)(n0 + rbase + srow8) * K + kb + sswz * 8,
                 Bs + rbase * 64);
    }
    __syncthreads();
#pragma unroll
    for (int ks = 0; ks < 2; ks++) {
      bf16x8 af[2], bfv[4];
      int ch = (ks * 4 + quad) ^ (l15 & 7);
#pragma unroll
      for (int t = 0; t < 2; t++)
        af[t] = *(const bf16x8*)(As + (wm * 32 + t * 16 + l15) * 64 + ch * 8);
#pragma unroll
      for (int t = 0; t < 4; t++)
        bfv[t] = *(const bf16x8*)(Bs + (wn * 64 + t * 16 + l15) * 64 + ch * 8);
#pragma unroll
      for (int mi = 0; mi < 2; mi++)
#pragma unroll
        for (int ni = 0; ni < 4; ni++)
          acc[mi][ni] = mfma16(af[mi], bfv[ni], acc[mi][ni]);
    }
  }

#pragma unroll
  for (int mi = 0; mi < 2; mi++)
#pragma unroll
    for (int ni = 0; ni < 4; ni++) {
      int n = n0 + wn * 64 + ni * 16 + l15;
#pragma unroll
      for (int r = 0; r < 4; r++) {
        int m = m0 + wm * 32 + mi * 16 + quad * 4 + r;
        Cout[(size_t)m * N + n] = acc[mi][ni][r] + bias[n];
      }
    }
}

// ---------------------------------------------------------------------------
// Barrier-free, LDS-free causal flash attention v7.
// EXACT R5 per-wave body (92 us, VGPR~128, no spills), launched as 512 blocks
// x 4 independent waves.  NO second __launch_bounds__ arg (R4/R7 lesson:
// any waves/EU hint here caps VGPR below need -> scratch spills).
// bid=(63-j)*8+bhg: waves in a block share strip length j (retire together);
// bh=bhg*4+wave; XCD=bid%8=bhg -> 4 heads/XCD (2 MB K/V, L2-resident).
// Masks BEFORE scale like the reference: masked -> -1e9/8 = -1.25e8.
// ---------------------------------------------------------------------------
__global__ __launch_bounds__(256)
void flash_attn(const __bf16* __restrict__ q, const __bf16* __restrict__ k,
                const __bf16* __restrict__ vt, const int* __restrict__ amask,
                __bf16* __restrict__ ctx) {
  const int S = 2048;
  const int bid = blockIdx.x;
  const int wave = threadIdx.x >> 6, lane = threadIdx.x & 63;
  const int j = 63 - (bid >> 3);    // strip index, heaviest first
  const int bh = (bid & 7) * 4 + wave;
  const int b = bh >> 4, h = bh & 15;
  const int quad = lane >> 4, l15 = lane & 15;
  const int q0 = j * 32;

  const __bf16* qp  = q  + (size_t)bh * S * 64;
  const __bf16* kp0 = k  + (size_t)bh * S * 64;
  const __bf16* vp0 = vt + (size_t)bh * 64 * S;

  bf16x8 qf[2][2];  // [mt][ks]
#pragma unroll
  for (int mt = 0; mt < 2; mt++)
#pragma unroll
    for (int ks = 0; ks < 2; ks++)
      qf[mt][ks] = *(const bf16x8*)(qp + (size_t)(q0 + mt * 16 + l15) * 64 +
                                    ks * 32 + quad * 8);

  float mrun[2] = {-3.0e38f, -3.0e38f}, lrun[2] = {0.0f, 0.0f};
  floatx4 oacc[2][4] = {};
  const int nch = ((q0 + 31) >> 6) + 1;  // 64-key chunks

  // shuffle sources for P transform (same l15 column, two quads)
  const int bsel = (quad & 1) * 2;
  const int srcA = bsel * 16 + l15;
  const int srcB = (bsel + 1) * 16 + l15;
  const bool hiTile = (quad >> 1) != 0;

  for (int c = 0; c < nch; c++) {
    const __bf16* kp = kp0 + (size_t)c * 64 * 64;
    floatx4 st[4][2] = {};  // st[key-tile][q-tile]; col(l15)=q, row(quad*4+r)=key
#pragma unroll
    for (int ks = 0; ks < 2; ks++) {
      bf16x8 kf[4];
#pragma unroll
      for (int nt = 0; nt < 4; nt++)
        kf[nt] = *(const bf16x8*)(kp + (size_t)(nt * 16 + l15) * 64 +
                                  ks * 32 + quad * 8);
#pragma unroll
      for (int nt = 0; nt < 4; nt++) {
        st[nt][0] = mfma16(kf[nt], qf[0][ks], st[nt][0]);
        st[nt][1] = mfma16(kf[nt], qf[1][ks], st[nt][1]);
      }
    }
    unsigned long long pm = __ballot(amask[b * S + c * 64 + lane] == 0);

    if (c == nch - 1) {  // wave-uniform: only last chunk can cross diagonal
#pragma unroll
      for (int nt = 0; nt < 4; nt++) {
        int kl = nt * 16 + quad * 4;
        int keyg = c * 64 + kl;
#pragma unroll
        for (int r = 0; r < 4; r++) {
          bool pad = (pm >> (kl + r)) & 1ull;
#pragma unroll
          for (int mt = 0; mt < 2; mt++) {
            float sv = st[nt][mt][r] * 0.125f;
            bool masked = pad || (keyg + r > q0 + mt * 16 + l15);
            st[nt][mt][r] = masked ? -1.25e8f : sv;
          }
        }
      }
    } else {
#pragma unroll
      for (int nt = 0; nt < 4; nt++) {
        int kl = nt * 16 + quad * 4;
#pragma unroll
        for (int r = 0; r < 4; r++) {
          bool pad = (pm >> (kl + r)) & 1ull;
#pragma unroll
          for (int mt = 0; mt < 2; mt++) {
            float sv = st[nt][mt][r] * 0.125f;
            st[nt][mt][r] = pad ? -1.25e8f : sv;
          }
        }
      }
    }

    // online softmax (per q = l15), tree reductions
    float al[2];
#pragma unroll
    for (int mt = 0; mt < 2; mt++) {
      float m4[4];
#pragma unroll
      for (int nt = 0; nt < 4; nt++)
        m4[nt] = fmaxf(fmaxf(st[nt][mt][0], st[nt][mt][1]),
                       fmaxf(st[nt][mt][2], st[nt][mt][3]));
      float rm = fmaxf(fmaxf(m4[0], m4[1]), fmaxf(m4[2], m4[3]));
      rm = fmaxf(rm, __shfl_xor(rm, 16, 64));
      rm = fmaxf(rm, __shfl_xor(rm, 32, 64));
      float mnew = fmaxf(mrun[mt], rm);
      al[mt] = exp2f((mrun[mt] - mnew) * LOG2E);
      mrun[mt] = mnew;
      float s4[4];
#pragma unroll
      for (int nt = 0; nt < 4; nt++) {
        float p0 = exp2f((st[nt][mt][0] - mnew) * LOG2E);
        float p1 = exp2f((st[nt][mt][1] - mnew) * LOG2E);
        float p2 = exp2f((st[nt][mt][2] - mnew) * LOG2E);
        float p3 = exp2f((st[nt][mt][3] - mnew) * LOG2E);
        st[nt][mt][0] = p0; st[nt][mt][1] = p1;
        st[nt][mt][2] = p2; st[nt][mt][3] = p3;
        s4[nt] = (p0 + p1) + (p2 + p3);
      }
      float rs = (s4[0] + s4[1]) + (s4[2] + s4[3]);
      rs += __shfl_xor(rs, 16, 64);
      rs += __shfl_xor(rs, 32, 64);
      lrun[mt] = lrun[mt] * al[mt] + rs;
    }

    // rescale O (alpha per O-row quad*4+r, fetched cross-lane)
#pragma unroll
    for (int mt = 0; mt < 2; mt++) {
      float ar[4];
#pragma unroll
      for (int r = 0; r < 4; r++) ar[r] = __shfl(al[mt], quad * 4 + r, 64);
#pragma unroll
      for (int nd = 0; nd < 4; nd++)
#pragma unroll
        for (int r = 0; r < 4; r++) oacc[mt][nd][r] *= ar[r];
    }

    // pack P to bf16 pairs: pk[nt][mt] = {keys r0r1, r2r3} for q=l15
    unsigned pkLo[4][2], pkHi[4][2];
#pragma unroll
    for (int nt = 0; nt < 4; nt++)
#pragma unroll
      for (int mt = 0; mt < 2; mt++) {
        pkLo[nt][mt] = pack_bf16(st[nt][mt][0], st[nt][mt][1]);
        pkHi[nt][mt] = pack_bf16(st[nt][mt][2], st[nt][mt][3]);
      }

    // O += P V over two 32-key subchunks; P A-frag via shuffles
#pragma unroll
    for (int s = 0; s < 2; s++) {
      bf16x8 pf[2];
#pragma unroll
      for (int mt = 0; mt < 2; mt++) {
        int t0 = s * 2, t1 = s * 2 + 1;
        unsigned u0a = __shfl((int)pkLo[t0][mt], srcA, 64);
        unsigned u0b = __shfl((int)pkLo[t1][mt], srcA, 64);
        unsigned u1a = __shfl((int)pkHi[t0][mt], srcA, 64);
        unsigned u1b = __shfl((int)pkHi[t1][mt], srcA, 64);
        unsigned u2a = __shfl((int)pkLo[t0][mt], srcB, 64);
        unsigned u2b = __shfl((int)pkLo[t1][mt], srcB, 64);
        unsigned u3a = __shfl((int)pkHi[t0][mt], srcB, 64);
        unsigned u3b = __shfl((int)pkHi[t1][mt], srcB, 64);
        unsigned u[4] = {hiTile ? u0b : u0a, hiTile ? u1b : u1a,
                         hiTile ? u2b : u2a, hiTile ? u3b : u3a};
        pf[mt] = *(bf16x8*)u;
      }
      const __bf16* vp = vp0 + c * 64 + s * 32;
#pragma unroll
      for (int nd = 0; nd < 4; nd++) {
        bf16x8 vf = *(const bf16x8*)(vp + (size_t)(nd * 16 + l15) * S + quad * 8);
        oacc[0][nd] = mfma16(pf[0], vf, oacc[0][nd]);
        oacc[1][nd] = mfma16(pf[1], vf, oacc[1][nd]);
      }
    }
  }

  // epilogue: ctx[b][s][h*64+dh] = O / l ;  O rows = quad*4+r
#pragma unroll
  for (int mt = 0; mt < 2; mt++) {
    float lr[4];
#pragma unroll
    for (int r = 0; r < 4; r++)
      lr[r] = 1.0f / __shfl(lrun[mt], quad * 4 + r, 64);
#pragma unroll
    for (int nd = 0; nd < 4; nd++) {
#pragma unroll
      for (int r = 0; r < 4; r++) {
        int s = q0 + mt * 16 + quad * 4 + r;
        int dh = nd * 16 + l15;
        ctx[((size_t)(b * 2048 + s)) * 1024 + h * 64 + dh] =
            (__bf16)(oacc[mt][nd][r] * lr[r]);
      }
    }
  }
}

// ---------------------------------------------------------------------------
extern "C" void kernel_launch(void* const* d_in, const int* in_sizes, int n_in,
                              void* d_out, int out_size, void* d_ws, size_t ws_size,
                              hipStream_t stream) {
  const float* x  = (const float*)d_in[0];
  const int*   am = (const int*)d_in[1];
  const float* Wq = (const float*)d_in[2];
  const float* bq = (const float*)d_in[3];
  const float* Aq = (const float*)d_in[4];
  const float* Bq = (const float*)d_in[5];
  const float* Wp = (const float*)d_in[6];
  const float* bp = (const float*)d_in[7];
  const float* Ap = (const float*)d_in[8];
  const float* Bp = (const float*)d_in[9];

  __bf16* wqkvT = (__bf16*)d_ws;                       // [3072][1024]
  __bf16* wpT   = wqkvT + (size_t)3072 * 1024;         // [1024][1024]
  __bf16* xbf   = wpT   + (size_t)1024 * 1024;         // [4096][1024]
  __bf16* qbuf  = xbf   + (size_t)4096 * 1024;         // [2][16][2048][64] (+kbuf)
  __bf16* vtbuf = qbuf  + (size_t)2 * 4194304;         // [2][16][64][2048]
  __bf16* ctxb  = vtbuf + (size_t)4194304;             // [4096][1024]

  fold_wt<<<dim3(48, 16), 256, 0, stream>>>(Wq, Aq, Bq, wqkvT, 3072);
  fold_wt<<<dim3(16, 16), 256, 0, stream>>>(Wp, Ap, Bp, wpT, 1024);
  cast_x<<<4096, 256, 0, stream>>>(x, xbf);

  gemm_qkv<<<dim3(32, 24), 256, 0, stream>>>(wqkvT, xbf, bq, qbuf, vtbuf);
  flash_attn<<<512, 256, 0, stream>>>(qbuf, qbuf + 4194304, vtbuf, am, ctxb);
  gemm_proj<<<dim3(8, 64), 256, 0, stream>>>(ctxb, wpT, bp, (float*)d_out, 1024);
}

// Round 9
// 236.451 us; speedup vs baseline: 1.3202x; 1.0735x over previous
//
#include <hip/hip_runtime.h>
#include <hip/hip_bf16.h>

#define LOG2E 1.4426950408889634f

typedef __bf16 bf16x8 __attribute__((ext_vector_type(8)));
typedef __bf16 bf16x4 __attribute__((ext_vector_type(4)));
typedef __bf16 bf16x2 __attribute__((ext_vector_type(2)));
typedef float  floatx4 __attribute__((ext_vector_type(4)));

__device__ __forceinline__ floatx4 mfma16(bf16x8 a, bf16x8 b, floatx4 c) {
  return __builtin_amdgcn_mfma_f32_16x16x32_bf16(a, b, c, 0, 0, 0);
}

// async global->LDS, 16B per lane. Dest = wave-uniform base + lane*16.
__device__ __forceinline__ void load_lds16(const __bf16* g, __bf16* l) {
  __builtin_amdgcn_global_load_lds(
      (const __attribute__((address_space(1))) void*)g,
      (__attribute__((address_space(3))) void*)l, 16, 0, 0);
}

__device__ __forceinline__ unsigned pack_bf16(float a, float b) {
  bf16x2 t = {(__bf16)a, (__bf16)b};
  return *(unsigned*)&t;
}

// ---------------------------------------------------------------------------
// Fold LoRA into weights, emit W_eff^T bf16 [ncols][1024].
// ---------------------------------------------------------------------------
__global__ __launch_bounds__(256)
void fold_wt(const float* __restrict__ W, const float* __restrict__ La,
             const float* __restrict__ Lb, __bf16* __restrict__ WT, int ncols) {
  __shared__ float tile[64][65];
  __shared__ float sLb[8][64];
  const int kt = blockIdx.y * 64, nt = blockIdx.x * 64;
  const int tid = threadIdx.x;
  const int tx = tid & 63, ty = tid >> 6;

  float rLa[8];
  *(float4*)&rLa[0] = *(const float4*)(La + (size_t)(kt + tx) * 8);
  *(float4*)&rLa[4] = *(const float4*)(La + (size_t)(kt + tx) * 8 + 4);

#pragma unroll
  for (int rep = 0; rep < 2; rep++) {
    int idx = tid + rep * 256;
    sLb[idx >> 6][idx & 63] = Lb[(size_t)(idx >> 6) * ncols + nt + (idx & 63)];
  }
#pragma unroll
  for (int rep = 0; rep < 16; rep++) {
    int i = rep * 4 + ty;
    tile[i][tx] = W[(size_t)(kt + i) * ncols + nt + tx];
  }
  __syncthreads();
#pragma unroll
  for (int rep = 0; rep < 16; rep++) {
    int i = rep * 4 + ty;
    int n = nt + i, k = kt + tx;
    float acc = tile[tx][i];
#pragma unroll
    for (int r = 0; r < 8; r++)
      acc += 2.0f * rLa[r] * sLb[r][i];  // LORA_SCALING = 2
    WT[(size_t)n * 1024 + k] = (__bf16)acc;
  }
}

__global__ __launch_bounds__(256)
void cast_x(const float* __restrict__ x, __bf16* __restrict__ o) {
  int i = blockIdx.x * 256 + threadIdx.x;
  float4 v = ((const float4*)x)[i];
  bf16x4 r = {(__bf16)v.x, (__bf16)v.y, (__bf16)v.z, (__bf16)v.w};
  ((bf16x4*)o)[i] = r;
}

// ---------------------------------------------------------------------------
// Fused QKV projection, swapped orientation: D[p][s] = sum_k WT[p][k] X[s][k].
// 128x128 tiles, BK=64, global_load_lds staging, XOR-swizzled LDS.
// Q channels (p<1024) are pre-scaled by 0.125 (exact pow2) so the flash
// kernel can skip the per-score scale; masked value stays -1e9/8.
// ---------------------------------------------------------------------------
__global__ __launch_bounds__(256)
void gemm_qkv(const __bf16* __restrict__ WT, const __bf16* __restrict__ X,
              const float* __restrict__ bias, __bf16* __restrict__ qk,
              __bf16* __restrict__ vtb) {
  const int K = 1024;
  __shared__ alignas(16) __bf16 As[128 * 64];
  __shared__ alignas(16) __bf16 Bs[128 * 64];
  const int tid = threadIdx.x;
  const int wave = tid >> 6, lane = tid & 63;
  const int wm = wave >> 1, wn = wave & 1;
  const int quad = lane >> 4, l15 = lane & 15;
  const int p0 = blockIdx.y * 128, s0 = blockIdx.x * 128;
  const int srow8 = lane >> 3, sc8 = lane & 7;
  const int sswz = sc8 ^ srow8;

  floatx4 acc[4][4] = {};

  for (int kb = 0; kb < K; kb += 64) {
    __syncthreads();
#pragma unroll
    for (int t = 0; t < 4; t++) {
      int rbase = (wave * 4 + t) * 8;
      int row = rbase + srow8;
      load_lds16(WT + (size_t)(p0 + row) * K + kb + sswz * 8, As + rbase * 64);
      load_lds16(X + (size_t)(s0 + row) * K + kb + sswz * 8, Bs + rbase * 64);
    }
    __syncthreads();
#pragma unroll
    for (int ks = 0; ks < 2; ks++) {
      bf16x8 af[4], bfv[4];
#pragma unroll
      for (int t = 0; t < 4; t++) {
        int ra = wm * 64 + t * 16 + l15;
        int rb = wn * 64 + t * 16 + l15;
        int ch = (ks * 4 + quad) ^ (l15 & 7);
        af[t]  = *(const bf16x8*)(As + ra * 64 + ch * 8);
        bfv[t] = *(const bf16x8*)(Bs + rb * 64 + ch * 8);
      }
#pragma unroll
      for (int mi = 0; mi < 4; mi++)
#pragma unroll
        for (int ni = 0; ni < 4; ni++)
          acc[mi][ni] = mfma16(af[mi], bfv[ni], acc[mi][ni]);
    }
  }

  const float qscale = (p0 < 1024) ? 0.125f : 1.0f;  // block-uniform
#pragma unroll
  for (int mi = 0; mi < 4; mi++) {
#pragma unroll
    for (int ni = 0; ni < 4; ni++) {
      int pb = p0 + wm * 64 + mi * 16 + quad * 4;  // channel base (mult of 4)
      int s  = s0 + wn * 64 + ni * 16 + l15;       // token
      int b = s >> 11, s2 = s & 2047;
      if (p0 < 2048) {  // q/k: uniform per block
        int part = pb >> 10, h = (pb & 1023) >> 6, dhb = pb & 63;
        bf16x4 o = {(__bf16)((acc[mi][ni][0] + bias[pb]) * qscale),
                    (__bf16)((acc[mi][ni][1] + bias[pb + 1]) * qscale),
                    (__bf16)((acc[mi][ni][2] + bias[pb + 2]) * qscale),
                    (__bf16)((acc[mi][ni][3] + bias[pb + 3]) * qscale)};
        *(bf16x4*)(qk + (size_t)part * 4194304 +
                   ((size_t)((b * 16 + h) * 2048 + s2)) * 64 + dhb) = o;
      } else {  // v -> v^T
        int h = (pb & 1023) >> 6, dhb = pb & 63;
#pragma unroll
        for (int r = 0; r < 4; r++)
          vtb[((size_t)((b * 16 + h) * 64 + dhb + r)) * 2048 + s2] =
              (__bf16)(acc[mi][ni][r] + bias[pb + r]);
      }
    }
  }
}

// ---------------------------------------------------------------------------
// Output projection, 64x128 tile: grid (8, 64) = 512 blocks.  fp32 out + bias.
// ---------------------------------------------------------------------------
__global__ __launch_bounds__(256)
void gemm_proj(const __bf16* __restrict__ A, const __bf16* __restrict__ BT,
               const float* __restrict__ bias, float* __restrict__ Cout, int N) {
  const int K = 1024;
  __shared__ alignas(16) __bf16 As[64 * 64];
  __shared__ alignas(16) __bf16 Bs[128 * 64];
  const int tid = threadIdx.x;
  const int wave = tid >> 6, lane = tid & 63;
  const int wm = wave >> 1, wn = wave & 1;
  const int quad = lane >> 4, l15 = lane & 15;
  const int m0 = blockIdx.y * 64, n0 = blockIdx.x * 128;
  const int srow8 = lane >> 3, sc8 = lane & 7;
  const int sswz = sc8 ^ srow8;

  floatx4 acc[2][4] = {};

  for (int kb = 0; kb < K; kb += 64) {
    __syncthreads();
#pragma unroll
    for (int t = 0; t < 2; t++) {
      int rbase = (wave * 2 + t) * 8;
      load_lds16(A + (size_t)(m0 + rbase + srow8) * K + kb + sswz * 8,
                 As + rbase * 64);
    }
#pragma unroll
    for (int t = 0; t < 4; t++) {
      int rbase = (wave * 4 + t) * 8;
      load_lds16(BT + (size_t)(n0 + rbase + srow8) * K + kb + sswz * 8,
                 Bs + rbase * 64);
    }
    __syncthreads();
#pragma unroll
    for (int ks = 0; ks < 2; ks++) {
      bf16x8 af[2], bfv[4];
      int ch = (ks * 4 + quad) ^ (l15 & 7);
#pragma unroll
      for (int t = 0; t < 2; t++)
        af[t] = *(const bf16x8*)(As + (wm * 32 + t * 16 + l15) * 64 + ch * 8);
#pragma unroll
      for (int t = 0; t < 4; t++)
        bfv[t] = *(const bf16x8*)(Bs + (wn * 64 + t * 16 + l15) * 64 + ch * 8);
#pragma unroll
      for (int mi = 0; mi < 2; mi++)
#pragma unroll
        for (int ni = 0; ni < 4; ni++)
          acc[mi][ni] = mfma16(af[mi], bfv[ni], acc[mi][ni]);
    }
  }

#pragma unroll
  for (int mi = 0; mi < 2; mi++)
#pragma unroll
    for (int ni = 0; ni < 4; ni++) {
      int n = n0 + wn * 64 + ni * 16 + l15;
#pragma unroll
      for (int r = 0; r < 4; r++) {
        int m = m0 + wm * 32 + mi * 16 + quad * 4 + r;
        Cout[(size_t)m * N + n] = acc[mi][ni][r] + bias[n];
      }
    }
}

// ---------------------------------------------------------------------------
// Causal flash attention v8: split-K x4.
// Block = 256 threads = 4 waves = ONE 32-q strip; wave w handles 64-key
// chunks c = w, w+4, ...  Each wave runs independent online softmax (exact
// R5 chunk body; q pre-scaled by 0.125 so no per-score mul); one
// __syncthreads + LDS merge (m*=max, l*=sum f*l, O*=sum f*O) at the end.
// 2048 blocks = 8192 waves (4x R5); VGPR~128 -> 4 blocks/CU resident.
// NO second __launch_bounds__ arg (R4/R7: any waves/EU hint -> spills).
// bid=(63-j)*32+...: waves in a block share strip (retire together);
// XCD=bid%8 -> 4 heads/XCD (3 MB Q/K/V, L2-resident).
// Masked value = -1e9/8 = -1.25e8 (reference masks before scale).
// ---------------------------------------------------------------------------
__global__ __launch_bounds__(256)
void flash_attn(const __bf16* __restrict__ q, const __bf16* __restrict__ k,
                const __bf16* __restrict__ vt, const int* __restrict__ amask,
                __bf16* __restrict__ ctx) {
  const int S = 2048;
  __shared__ float mbuf[3][36][64];  // [wave-1][elem][lane], conflict-free
  const int bid = blockIdx.x;
  const int wave = threadIdx.x >> 6, lane = threadIdx.x & 63;
  const int j = 63 - (bid >> 5);               // strip, heaviest first
  const int bh = (bid & 7) * 4 + ((bid >> 3) & 3);
  const int b = bh >> 4, h = bh & 15;
  const int quad = lane >> 4, l15 = lane & 15;
  const int q0 = j * 32;

  const __bf16* qp  = q  + (size_t)bh * S * 64;
  const __bf16* kp0 = k  + (size_t)bh * S * 64;
  const __bf16* vp0 = vt + (size_t)bh * 64 * S;

  bf16x8 qf[2][2];  // [mt][ks]
#pragma unroll
  for (int mt = 0; mt < 2; mt++)
#pragma unroll
    for (int ks = 0; ks < 2; ks++)
      qf[mt][ks] = *(const bf16x8*)(qp + (size_t)(q0 + mt * 16 + l15) * 64 +
                                    ks * 32 + quad * 8);

  float mrun[2] = {-1.0e30f, -1.0e30f}, lrun[2] = {0.0f, 0.0f};
  floatx4 oacc[2][4] = {};
  const int nch = ((q0 + 31) >> 6) + 1;  // 64-key chunks

  // shuffle sources for P transform (same l15 column, two quads)
  const int bsel = (quad & 1) * 2;
  const int srcA = bsel * 16 + l15;
  const int srcB = (bsel + 1) * 16 + l15;
  const bool hiTile = (quad >> 1) != 0;

  for (int c = wave; c < nch; c += 4) {
    const __bf16* kp = kp0 + (size_t)c * 64 * 64;
    floatx4 st[4][2] = {};  // st[key-tile][q-tile]; col(l15)=q, row(quad*4+r)=key
#pragma unroll
    for (int ks = 0; ks < 2; ks++) {
      bf16x8 kf[4];
#pragma unroll
      for (int nt = 0; nt < 4; nt++)
        kf[nt] = *(const bf16x8*)(kp + (size_t)(nt * 16 + l15) * 64 +
                                  ks * 32 + quad * 8);
#pragma unroll
      for (int nt = 0; nt < 4; nt++) {
        st[nt][0] = mfma16(kf[nt], qf[0][ks], st[nt][0]);
        st[nt][1] = mfma16(kf[nt], qf[1][ks], st[nt][1]);
      }
    }
    unsigned long long pm = __ballot(amask[b * S + c * 64 + lane] == 0);

    if (c == nch - 1) {  // wave-uniform: only the diagonal chunk needs causal
#pragma unroll
      for (int nt = 0; nt < 4; nt++) {
        int kl = nt * 16 + quad * 4;
        int keyg = c * 64 + kl;
#pragma unroll
        for (int r = 0; r < 4; r++) {
          bool pad = (pm >> (kl + r)) & 1ull;
#pragma unroll
          for (int mt = 0; mt < 2; mt++) {
            bool masked = pad || (keyg + r > q0 + mt * 16 + l15);
            st[nt][mt][r] = masked ? -1.25e8f : st[nt][mt][r];
          }
        }
      }
    } else {
#pragma unroll
      for (int nt = 0; nt < 4; nt++) {
        int kl = nt * 16 + quad * 4;
#pragma unroll
        for (int r = 0; r < 4; r++) {
          bool pad = (pm >> (kl + r)) & 1ull;
#pragma unroll
          for (int mt = 0; mt < 2; mt++)
            st[nt][mt][r] = pad ? -1.25e8f : st[nt][mt][r];
        }
      }
    }

    // online softmax (per q = l15), tree reductions
    float al[2];
#pragma unroll
    for (int mt = 0; mt < 2; mt++) {
      float m4[4];
#pragma unroll
      for (int nt = 0; nt < 4; nt++)
        m4[nt] = fmaxf(fmaxf(st[nt][mt][0], st[nt][mt][1]),
                       fmaxf(st[nt][mt][2], st[nt][mt][3]));
      float rm = fmaxf(fmaxf(m4[0], m4[1]), fmaxf(m4[2], m4[3]));
      rm = fmaxf(rm, __shfl_xor(rm, 16, 64));
      rm = fmaxf(rm, __shfl_xor(rm, 32, 64));
      float mnew = fmaxf(mrun[mt], rm);
      al[mt] = exp2f((mrun[mt] - mnew) * LOG2E);
      mrun[mt] = mnew;
      float s4[4];
#pragma unroll
      for (int nt = 0; nt < 4; nt++) {
        float p0 = exp2f((st[nt][mt][0] - mnew) * LOG2E);
        float p1 = exp2f((st[nt][mt][1] - mnew) * LOG2E);
        float p2 = exp2f((st[nt][mt][2] - mnew) * LOG2E);
        float p3 = exp2f((st[nt][mt][3] - mnew) * LOG2E);
        st[nt][mt][0] = p0; st[nt][mt][1] = p1;
        st[nt][mt][2] = p2; st[nt][mt][3] = p3;
        s4[nt] = (p0 + p1) + (p2 + p3);
      }
      float rs = (s4[0] + s4[1]) + (s4[2] + s4[3]);
      rs += __shfl_xor(rs, 16, 64);
      rs += __shfl_xor(rs, 32, 64);
      lrun[mt] = lrun[mt] * al[mt] + rs;
    }

    // rescale O (alpha per O-row quad*4+r, fetched cross-lane)
#pragma unroll
    for (int mt = 0; mt < 2; mt++) {
      float ar[4];
#pragma unroll
      for (int r = 0; r < 4; r++) ar[r] = __shfl(al[mt], quad * 4 + r, 64);
#pragma unroll
      for (int nd = 0; nd < 4; nd++)
#pragma unroll
        for (int r = 0; r < 4; r++) oacc[mt][nd][r] *= ar[r];
    }

    // pack P to bf16 pairs: pk[nt][mt] = {keys r0r1, r2r3} for q=l15
    unsigned pkLo[4][2], pkHi[4][2];
#pragma unroll
    for (int nt = 0; nt < 4; nt++)
#pragma unroll
      for (int mt = 0; mt < 2; mt++) {
        pkLo[nt][mt] = pack_bf16(st[nt][mt][0], st[nt][mt][1]);
        pkHi[nt][mt] = pack_bf16(st[nt][mt][2], st[nt][mt][3]);
      }

    // O += P V over two 32-key subchunks; P A-frag via shuffles
#pragma unroll
    for (int s = 0; s < 2; s++) {
      bf16x8 pf[2];
#pragma unroll
      for (int mt = 0; mt < 2; mt++) {
        int t0 = s * 2, t1 = s * 2 + 1;
        unsigned u0a = __shfl((int)pkLo[t0][mt], srcA, 64);
        unsigned u0b = __shfl((int)pkLo[t1][mt], srcA, 64);
        unsigned u1a = __shfl((int)pkHi[t0][mt], srcA, 64);
        unsigned u1b = __shfl((int)pkHi[t1][mt], srcA, 64);
        unsigned u2a = __shfl((int)pkLo[t0][mt], srcB, 64);
        unsigned u2b = __shfl((int)pkLo[t1][mt], srcB, 64);
        unsigned u3a = __shfl((int)pkHi[t0][mt], srcB, 64);
        unsigned u3b = __shfl((int)pkHi[t1][mt], srcB, 64);
        unsigned u[4] = {hiTile ? u0b : u0a, hiTile ? u1b : u1a,
                         hiTile ? u2b : u2a, hiTile ? u3b : u3a};
        pf[mt] = *(bf16x8*)u;
      }
      const __bf16* vp = vp0 + c * 64 + s * 32;
#pragma unroll
      for (int nd = 0; nd < 4; nd++) {
        bf16x8 vf = *(const bf16x8*)(vp + (size_t)(nd * 16 + l15) * S + quad * 8);
        oacc[0][nd] = mfma16(pf[0], vf, oacc[0][nd]);
        oacc[1][nd] = mfma16(pf[1], vf, oacc[1][nd]);
      }
    }
  }

  // ---- split-K merge: waves 1-3 publish (O, m, l); wave 0 combines ----
  if (wave != 0) {
    int w = wave - 1;
#pragma unroll
    for (int mt = 0; mt < 2; mt++)
#pragma unroll
      for (int nd = 0; nd < 4; nd++)
#pragma unroll
        for (int r = 0; r < 4; r++)
          mbuf[w][(mt * 4 + nd) * 4 + r][lane] = oacc[mt][nd][r];
#pragma unroll
    for (int mt = 0; mt < 2; mt++) {
      mbuf[w][32 + mt][lane] = mrun[mt];
      mbuf[w][34 + mt][lane] = lrun[mt];
    }
  }
  __syncthreads();
  if (wave != 0) return;

  // merged max / combine factors (per q = l15; uniform across quads)
  float mw[3][2], lw[3][2], mstar[2], f0[2], fw[3][2], lstar[2];
#pragma unroll
  for (int w = 0; w < 3; w++)
#pragma unroll
    for (int mt = 0; mt < 2; mt++) {
      mw[w][mt] = mbuf[w][32 + mt][lane];
      lw[w][mt] = mbuf[w][34 + mt][lane];
    }
#pragma unroll
  for (int mt = 0; mt < 2; mt++) {
    mstar[mt] = fmaxf(fmaxf(mrun[mt], mw[0][mt]), fmaxf(mw[1][mt], mw[2][mt]));
    f0[mt] = exp2f((mrun[mt] - mstar[mt]) * LOG2E);
    lstar[mt] = f0[mt] * lrun[mt];
#pragma unroll
    for (int w = 0; w < 3; w++) {
      fw[w][mt] = exp2f((mw[w][mt] - mstar[mt]) * LOG2E);
      lstar[mt] += fw[w][mt] * lw[w][mt];
    }
  }

  // epilogue: O rows are q = mt*16 + quad*4 + r -> fetch factors cross-lane
#pragma unroll
  for (int mt = 0; mt < 2; mt++) {
    float f0r[4], fwr[3][4], lr[4];
#pragma unroll
    for (int r = 0; r < 4; r++) {
      f0r[r] = __shfl(f0[mt], quad * 4 + r, 64);
      lr[r]  = __shfl(lstar[mt], quad * 4 + r, 64);
#pragma unroll
      for (int w = 0; w < 3; w++)
        fwr[w][r] = __shfl(fw[w][mt], quad * 4 + r, 64);
    }
#pragma unroll
    for (int r = 0; r < 4; r++) lr[r] = 1.0f / lr[r];
#pragma unroll
    for (int nd = 0; nd < 4; nd++) {
#pragma unroll
      for (int r = 0; r < 4; r++) {
        float ov = f0r[r] * oacc[mt][nd][r];
#pragma unroll
        for (int w = 0; w < 3; w++)
          ov += fwr[w][r] * mbuf[w][(mt * 4 + nd) * 4 + r][lane];
        int s = q0 + mt * 16 + quad * 4 + r;
        int dh = nd * 16 + l15;
        ctx[((size_t)(b * 2048 + s)) * 1024 + h * 64 + dh] =
            (__bf16)(ov * lr[r]);
      }
    }
  }
}

// ---------------------------------------------------------------------------
extern "C" void kernel_launch(void* const* d_in, const int* in_sizes, int n_in,
                              void* d_out, int out_size, void* d_ws, size_t ws_size,
                              hipStream_t stream) {
  const float* x  = (const float*)d_in[0];
  const int*   am = (const int*)d_in[1];
  const float* Wq = (const float*)d_in[2];
  const float* bq = (const float*)d_in[3];
  const float* Aq = (const float*)d_in[4];
  const float* Bq = (const float*)d_in[5];
  const float* Wp = (const float*)d_in[6];
  const float* bp = (const float*)d_in[7];
  const float* Ap = (const float*)d_in[8];
  const float* Bp = (const float*)d_in[9];

  __bf16* wqkvT = (__bf16*)d_ws;                       // [3072][1024]
  __bf16* wpT   = wqkvT + (size_t)3072 * 1024;         // [1024][1024]
  __bf16* xbf   = wpT   + (size_t)1024 * 1024;         // [4096][1024]
  __bf16* qbuf  = xbf   + (size_t)4096 * 1024;         // [2][16][2048][64] (+kbuf)
  __bf16* vtbuf = qbuf  + (size_t)2 * 4194304;         // [2][16][64][2048]
  __bf16* ctxb  = vtbuf + (size_t)4194304;             // [4096][1024]

  fold_wt<<<dim3(48, 16), 256, 0, stream>>>(Wq, Aq, Bq, wqkvT, 3072);
  fold_wt<<<dim3(16, 16), 256, 0, stream>>>(Wp, Ap, Bp, wpT, 1024);
  cast_x<<<4096, 256, 0, stream>>>(x, xbf);

  gemm_qkv<<<dim3(32, 24), 256, 0, stream>>>(wqkvT, xbf, bq, qbuf, vtbuf);
  flash_attn<<<2048, 256, 0, stream>>>(qbuf, qbuf + 4194304, vtbuf, am, ctxb);
  gemm_proj<<<dim3(8, 64), 256, 0, stream>>>(ctxb, wpT, bp, (float*)d_out, 1024);
}